// Round 1
// baseline (401.327 us; speedup 1.0000x reference)
//
#include <hip/hip_runtime.h>
#include <hip/hip_bf16.h>
#include <math.h>

// ---------------------------------------------------------------------------
// out[s] = (sum_i gate_i * x_i) @ Wm + (sum_i gate_i) * bm
// gate_i = w_i^pow * exp(g_i - gmax_s) / (gsum_s + 1e-10),  g_i = x_i . Wg + bg
// index is SORTED -> segments are contiguous row ranges.
// ---------------------------------------------------------------------------

// K1: seg_start[s] = first row i with index[i] >= s ; seg_start[S] = N
__global__ __launch_bounds__(256) void k1_seg_offsets(const int* __restrict__ index,
                                                      int* __restrict__ seg_start,
                                                      int N, int S) {
    int i = blockIdx.x * blockDim.x + threadIdx.x;
    if (i >= N) return;
    int cur  = index[i];
    int prev = (i == 0) ? -1 : index[i - 1];
    for (int s = prev + 1; s <= cur; ++s) seg_start[s] = i;
    if (i == N - 1) {
        for (int s = cur + 1; s <= S; ++s) seg_start[s] = N;
    }
}

// K2: one wave per segment. Online (flash-style) softmax over the segment's
// rows while accumulating the gate-weighted feature sum. Single pass over x.
__global__ __launch_bounds__(256) void k2_seg_softmax_pool(
    const float* __restrict__ x, const float* __restrict__ w,
    const float* __restrict__ Wg, const float* __restrict__ bg,
    const float* __restrict__ pw_, const int* __restrict__ seg_start,
    float* __restrict__ t, float* __restrict__ sgate, int S) {
    int gwid = (int)((blockIdx.x * 256 + threadIdx.x) >> 6);
    int lane = threadIdx.x & 63;
    if (gwid >= S) return;
    int start = seg_start[gwid], end = seg_start[gwid + 1];

    float2 wg  = *reinterpret_cast<const float2*>(Wg + 2 * lane);
    float  bgv = bg[0];
    float  pw  = pw_[0];

    float m = -INFINITY, ssum = 0.f;
    float accx = 0.f, accy = 0.f;

    float2 xv = make_float2(0.f, 0.f);
    if (start < end)
        xv = *reinterpret_cast<const float2*>(x + (size_t)start * 128 + 2 * lane);

    for (int i = start; i < end; ++i) {
        // software prefetch of next row (keeps 2 rows in flight per wave)
        float2 xn = make_float2(0.f, 0.f);
        if (i + 1 < end)
            xn = *reinterpret_cast<const float2*>(x + (size_t)(i + 1) * 128 + 2 * lane);
        float wi = w[i];

        // g_i = x_i . Wg + bg  (wave-wide reduction, all lanes get result)
        float p = xv.x * wg.x + xv.y * wg.y;
        #pragma unroll
        for (int off = 1; off < 64; off <<= 1) p += __shfl_xor(p, off);
        float g = p + bgv;

        // online softmax update
        float mn = fmaxf(m, g);
        float sc = expf(m - mn);              // m=-inf first iter -> sc=0
        float e  = powf(wi, pw) * expf(g - mn);
        ssum = ssum * sc + e;
        accx = accx * sc + e * xv.x;
        accy = accy * sc + e * xv.y;
        m = mn;
        xv = xn;
    }

    float inv = 1.f / (ssum + 1e-10f);
    *reinterpret_cast<float2*>(t + (size_t)gwid * 128 + 2 * lane) =
        make_float2(accx * inv, accy * inv);
    if (lane == 0) sgate[gwid] = ssum * inv;   // sum of normalized gates
}

// K3: out[row][:] = t[row][:] @ Wm + sgate[row] * bm
// Wm staged in LDS as lane-paired float2 (cols d and d+64) -> ds_read_b64,
// t rows read via wave-uniform base (readfirstlane) -> scalar loads.
__global__ __launch_bounds__(256) void k3_out_gemm(
    const float* __restrict__ t, const float* __restrict__ Wm,
    const float* __restrict__ bm, const float* __restrict__ sgate,
    float* __restrict__ out, int S) {
    __shared__ float2 lwm[128][64];   // 64 KiB: lwm[k][l] = (Wm[k][l], Wm[k][l+64])
    int tid = threadIdx.x;
    for (int idx = tid; idx < 128 * 64; idx += 256) {
        int k = idx >> 6, l = idx & 63;
        lwm[k][l] = make_float2(Wm[k * 128 + l], Wm[k * 128 + 64 + l]);
    }
    __syncthreads();

    int wave = tid >> 6, lane = tid & 63;
    int row0 = (blockIdx.x * 4 + wave) * 8;       // 8 rows per wave
    if (row0 >= S) return;

    const float* tb = t + (size_t)__builtin_amdgcn_readfirstlane(row0) * 128;

    float accx[8], accy[8];
    #pragma unroll
    for (int r = 0; r < 8; ++r) { accx[r] = 0.f; accy[r] = 0.f; }

    for (int k = 0; k < 128; k += 4) {
        float2 w0 = lwm[k][lane],     w1 = lwm[k + 1][lane];
        float2 w2 = lwm[k + 2][lane], w3 = lwm[k + 3][lane];
        #pragma unroll
        for (int r = 0; r < 8; ++r) {
            const float* tr = tb + r * 128 + k;   // uniform -> s_load_dwordx4
            float t0 = tr[0], t1 = tr[1], t2 = tr[2], t3 = tr[3];
            accx[r] += t0 * w0.x; accy[r] += t0 * w0.y;
            accx[r] += t1 * w1.x; accy[r] += t1 * w1.y;
            accx[r] += t2 * w2.x; accy[r] += t2 * w2.y;
            accx[r] += t3 * w3.x; accy[r] += t3 * w3.y;
        }
    }

    float bmx = bm[lane], bmy = bm[lane + 64];
    #pragma unroll
    for (int r = 0; r < 8; ++r) {
        int row = row0 + r;
        if (row < S) {
            float sg = sgate[row];
            out[(size_t)row * 128 + lane]      = accx[r] + sg * bmx;
            out[(size_t)row * 128 + lane + 64] = accy[r] + sg * bmy;
        }
    }
}

extern "C" void kernel_launch(void* const* d_in, const int* in_sizes, int n_in,
                              void* d_out, int out_size, void* d_ws, size_t ws_size,
                              hipStream_t stream) {
    const float* x       = (const float*)d_in[0];
    const float* weights = (const float*)d_in[1];
    const float* Wg      = (const float*)d_in[2];
    const float* bg      = (const float*)d_in[3];
    const float* Wm      = (const float*)d_in[4];
    const float* bm      = (const float*)d_in[5];
    const float* pow_    = (const float*)d_in[6];
    const int*   index   = (const int*)d_in[7];
    float* out = (float*)d_out;

    int N = in_sizes[1];          // weights is [N,1]
    int S = out_size / 128;       // out is [S,128]

    // workspace layout
    char* ws = (char*)d_ws;
    int* seg_start = (int*)ws;                                  // (S+1) ints
    size_t off = (((size_t)(S + 1) * 4) + 255) & ~(size_t)255;
    float* sgate = (float*)(ws + off);                          // S floats
    off += (((size_t)S * 4) + 255) & ~(size_t)255;
    float* t = (float*)(ws + off);                              // (S+32)*128 floats (pad for K3 over-read)

    k1_seg_offsets<<<(N + 255) / 256, 256, 0, stream>>>(index, seg_start, N, S);
    k2_seg_softmax_pool<<<(S + 3) / 4, 256, 0, stream>>>(x, weights, Wg, bg, pow_,
                                                         seg_start, t, sgate, S);
    k3_out_gemm<<<(S + 31) / 32, 256, 0, stream>>>(t, Wm, bm, sgate, out, S);
}

// Round 2
// 232.223 us; speedup vs baseline: 1.7282x; 1.7282x over previous
//
#include <hip/hip_runtime.h>
#include <hip/hip_bf16.h>
#include <math.h>

// ---------------------------------------------------------------------------
// out[s] = (sum_i gate_i * x_i) @ Wm + (sum_i gate_i) * bm
// gate_i = softmax-with-eps over h_i = x_i.Wg + bg + pow*ln(w_i)
// index is SORTED -> segments are contiguous row ranges.
// ---------------------------------------------------------------------------

// K1: seg_start[s] = first row i with index[i] >= s ; seg_start[S] = N
__global__ __launch_bounds__(256) void k1_seg_offsets(const int* __restrict__ index,
                                                      int* __restrict__ seg_start,
                                                      int N, int S) {
    int i = blockIdx.x * blockDim.x + threadIdx.x;
    if (i >= N) return;
    int cur  = index[i];
    int prev = (i == 0) ? -1 : index[i - 1];
    for (int s = prev + 1; s <= cur; ++s) seg_start[s] = i;
    if (i == N - 1) {
        for (int s = cur + 1; s <= S; ++s) seg_start[s] = N;
    }
}

// K2: one wave per segment, CHUNKED online softmax (16 rows per chunk).
// Per chunk: 16 independent partial dots -> 16 interleaved butterflies
// (pipelined, no serial chain) -> one rescale for the whole chunk.
#define CHUNK 16
__global__ __launch_bounds__(256) void k2_seg_softmax_pool(
    const float* __restrict__ x, const float* __restrict__ w,
    const float* __restrict__ Wg, const float* __restrict__ bg,
    const float* __restrict__ pw_, const int* __restrict__ seg_start,
    float* __restrict__ t, float* __restrict__ sgate, int S) {
    int gwid = (int)((blockIdx.x * 256 + threadIdx.x) >> 6);
    int lane = threadIdx.x & 63;
    if (gwid >= S) return;
    int start = seg_start[gwid], end = seg_start[gwid + 1];

    float2 wg  = *reinterpret_cast<const float2*>(Wg + 2 * lane);
    float  bgv = bg[0];
    float  pw  = pw_[0];

    float m = -INFINITY, ssum = 0.f;
    float accx = 0.f, accy = 0.f;

    for (int i0 = start; i0 < end; i0 += CHUNK) {
        int cnt = end - i0;               // rows in this chunk (>=1)
        if (cnt > CHUNK) cnt = CHUNK;

        // load 16 rows (coalesced float2 per lane), independent
        float2 xv[CHUNK];
        float  p[CHUNK];
        #pragma unroll
        for (int r = 0; r < CHUNK; ++r)
            xv[r] = (r < cnt)
                ? *reinterpret_cast<const float2*>(x + (size_t)(i0 + r) * 128 + 2 * lane)
                : make_float2(0.f, 0.f);

        // 16 independent partial dots
        #pragma unroll
        for (int r = 0; r < CHUNK; ++r)
            p[r] = xv[r].x * wg.x + xv[r].y * wg.y;

        // 16 butterflies, interleaved across levels -> fully pipelined
        #pragma unroll
        for (int off = 1; off < 64; off <<= 1) {
            #pragma unroll
            for (int r = 0; r < CHUNK; ++r)
                p[r] += __shfl_xor(p[r], off);
        }

        // h_r = g_r + pow*ln(w_r)  (broadcast same-address w load)
        float h[CHUNK];
        #pragma unroll
        for (int r = 0; r < CHUNK; ++r)
            h[r] = (r < cnt) ? (p[r] + bgv + pw * __logf(w[i0 + r])) : -INFINITY;

        // chunk max, one online rescale
        float cm = h[0];
        #pragma unroll
        for (int r = 1; r < CHUNK; ++r) cm = fmaxf(cm, h[r]);
        float mn = fmaxf(m, cm);
        float sc = __expf(m - mn);        // first chunk: exp(-inf)=0
        ssum *= sc; accx *= sc; accy *= sc;

        #pragma unroll
        for (int r = 0; r < CHUNK; ++r) {
            float e = __expf(h[r] - mn);  // r>=cnt: h=-inf -> e=0
            ssum += e;
            accx += e * xv[r].x;
            accy += e * xv[r].y;
        }
        m = mn;
    }

    float inv = 1.f / (ssum + 1e-10f);
    *reinterpret_cast<float2*>(t + (size_t)gwid * 128 + 2 * lane) =
        make_float2(accx * inv, accy * inv);
    if (lane == 0) sgate[gwid] = ssum * inv;   // sum of normalized gates
}

// K3: out[row][:] = t[row][:] @ Wm + sgate[row] * bm
__global__ __launch_bounds__(256) void k3_out_gemm(
    const float* __restrict__ t, const float* __restrict__ Wm,
    const float* __restrict__ bm, const float* __restrict__ sgate,
    float* __restrict__ out, int S) {
    __shared__ float2 lwm[128][64];   // 64 KiB: lwm[k][l] = (Wm[k][l], Wm[k][l+64])
    int tid = threadIdx.x;
    for (int idx = tid; idx < 128 * 64; idx += 256) {
        int k = idx >> 6, l = idx & 63;
        lwm[k][l] = make_float2(Wm[k * 128 + l], Wm[k * 128 + 64 + l]);
    }
    __syncthreads();

    int wave = tid >> 6, lane = tid & 63;
    int row0 = (blockIdx.x * 4 + wave) * 8;       // 8 rows per wave
    if (row0 >= S) return;

    const float* tb = t + (size_t)__builtin_amdgcn_readfirstlane(row0) * 128;

    float accx[8], accy[8];
    #pragma unroll
    for (int r = 0; r < 8; ++r) { accx[r] = 0.f; accy[r] = 0.f; }

    for (int k = 0; k < 128; k += 4) {
        float2 w0 = lwm[k][lane],     w1 = lwm[k + 1][lane];
        float2 w2 = lwm[k + 2][lane], w3 = lwm[k + 3][lane];
        #pragma unroll
        for (int r = 0; r < 8; ++r) {
            const float* tr = tb + r * 128 + k;   // uniform -> s_load
            float t0 = tr[0], t1 = tr[1], t2 = tr[2], t3 = tr[3];
            accx[r] += t0 * w0.x; accy[r] += t0 * w0.y;
            accx[r] += t1 * w1.x; accy[r] += t1 * w1.y;
            accx[r] += t2 * w2.x; accy[r] += t2 * w2.y;
            accx[r] += t3 * w3.x; accy[r] += t3 * w3.y;
        }
    }

    float bmx = bm[lane], bmy = bm[lane + 64];
    #pragma unroll
    for (int r = 0; r < 8; ++r) {
        int row = row0 + r;
        if (row < S) {
            float sg = sgate[row];
            out[(size_t)row * 128 + lane]      = accx[r] + sg * bmx;
            out[(size_t)row * 128 + lane + 64] = accy[r] + sg * bmy;
        }
    }
}

extern "C" void kernel_launch(void* const* d_in, const int* in_sizes, int n_in,
                              void* d_out, int out_size, void* d_ws, size_t ws_size,
                              hipStream_t stream) {
    const float* x       = (const float*)d_in[0];
    const float* weights = (const float*)d_in[1];
    const float* Wg      = (const float*)d_in[2];
    const float* bg      = (const float*)d_in[3];
    const float* Wm      = (const float*)d_in[4];
    const float* bm      = (const float*)d_in[5];
    const float* pow_    = (const float*)d_in[6];
    const int*   index   = (const int*)d_in[7];
    float* out = (float*)d_out;

    int N = in_sizes[1];          // weights is [N,1]
    int S = out_size / 128;       // out is [S,128]

    // workspace layout
    char* ws = (char*)d_ws;
    int* seg_start = (int*)ws;                                  // (S+1) ints
    size_t off = (((size_t)(S + 1) * 4) + 255) & ~(size_t)255;
    float* sgate = (float*)(ws + off);                          // S floats
    off += (((size_t)S * 4) + 255) & ~(size_t)255;
    float* t = (float*)(ws + off);                              // (S+32)*128 floats (pad for K3 over-read)

    k1_seg_offsets<<<(N + 255) / 256, 256, 0, stream>>>(index, seg_start, N, S);
    k2_seg_softmax_pool<<<(S + 3) / 4, 256, 0, stream>>>(x, weights, Wg, bg, pow_,
                                                         seg_start, t, sgate, S);
    k3_out_gemm<<<(S + 31) / 32, 256, 0, stream>>>(t, Wm, bm, sgate, out, S);
}

// Round 3
// 167.573 us; speedup vs baseline: 2.3949x; 1.3858x over previous
//
#include <hip/hip_runtime.h>
#include <hip/hip_bf16.h>
#include <math.h>

// ---------------------------------------------------------------------------
// out[s] = (sum_i gate_i * x_i) @ Wm + (sum_i gate_i) * bm
// gate_i = softmax-with-eps over h_i = x_i.Wg + bg + pow*ln(w_i)
// index is SORTED -> segments are contiguous row ranges.
// ---------------------------------------------------------------------------

// K1: seg_start[s] = first row i with index[i] >= s ; seg_start[S] = N
__global__ __launch_bounds__(256) void k1_seg_offsets(const int* __restrict__ index,
                                                      int* __restrict__ seg_start,
                                                      int N, int S) {
    int i = blockIdx.x * blockDim.x + threadIdx.x;
    if (i >= N) return;
    int cur  = index[i];
    int prev = (i == 0) ? -1 : index[i - 1];
    for (int s = prev + 1; s <= cur; ++s) seg_start[s] = i;
    if (i == N - 1) {
        for (int s = cur + 1; s <= S; ++s) seg_start[s] = N;
    }
}

// K2: one wave per segment; wave = 4 groups x 16 lanes; each group owns one
// row per 4-row step (float8 per lane). Per-group online softmax with
// defer-rescale (THR=8), flash-combine across groups at the end.
__global__ __launch_bounds__(256) void k2_seg_softmax_pool(
    const float* __restrict__ x, const float* __restrict__ w,
    const float* __restrict__ Wg, const float* __restrict__ bg,
    const float* __restrict__ pw_, const int* __restrict__ seg_start,
    float* __restrict__ t, float* __restrict__ sgate, int S) {
    int gwid = (int)((blockIdx.x * 256 + threadIdx.x) >> 6);
    if (gwid >= S) return;
    int lane = threadIdx.x & 63;
    int grp  = lane >> 4;        // which row of the 4-row step
    int pos  = lane & 15;        // feature slice [8*pos, 8*pos+8)

    int start = seg_start[gwid], end = seg_start[gwid + 1];

    float4 wg0 = *reinterpret_cast<const float4*>(Wg + pos * 8);
    float4 wg1 = *reinterpret_cast<const float4*>(Wg + pos * 8 + 4);
    float bgv = bg[0];
    float pw  = pw_[0];

    float mg = -INFINITY, ssum = 0.f;
    float acc[8];
    #pragma unroll
    for (int j = 0; j < 8; ++j) acc[j] = 0.f;

    if (start < end) {
        // prefetch step 0
        int row0 = start + grp;
        bool v0 = row0 < end;
        const float* xp0 = x + (size_t)row0 * 128 + pos * 8;
        float4 a = v0 ? *reinterpret_cast<const float4*>(xp0)     : make_float4(0,0,0,0);
        float4 b = v0 ? *reinterpret_cast<const float4*>(xp0 + 4) : make_float4(0,0,0,0);
        float wv = v0 ? w[row0] : 1.f;

        for (int i0 = start; i0 < end; i0 += 4) {
            // prefetch next step (keeps HBM latency off the chain)
            int rn = i0 + 4 + grp;
            bool vn = rn < end;
            const float* xpn = x + (size_t)rn * 128 + pos * 8;
            float4 an = vn ? *reinterpret_cast<const float4*>(xpn)     : make_float4(0,0,0,0);
            float4 bn = vn ? *reinterpret_cast<const float4*>(xpn + 4) : make_float4(0,0,0,0);
            float wn = vn ? w[rn] : 1.f;

            bool v = (i0 + grp) < end;
            // dot over this group's 16 lanes
            float p = a.x*wg0.x + a.y*wg0.y + a.z*wg0.z + a.w*wg0.w
                    + b.x*wg1.x + b.y*wg1.y + b.z*wg1.z + b.w*wg1.w;
            p += __shfl_xor(p, 1);
            p += __shfl_xor(p, 2);
            p += __shfl_xor(p, 4);
            p += __shfl_xor(p, 8);
            float h = v ? (p + bgv + pw * __logf(wv)) : -1e30f;

            if (v && h > mg + 8.f) {        // defer-rescale: rarely taken
                float sc = __expf(mg - h);  // mg=-inf first time -> 0
                ssum *= sc;
                #pragma unroll
                for (int j = 0; j < 8; ++j) acc[j] *= sc;
                mg = h;
            }
            float e = v ? __expf(h - mg) : 0.f;   // bounded by e^8
            ssum += e;
            acc[0] += e * a.x; acc[1] += e * a.y; acc[2] += e * a.z; acc[3] += e * a.w;
            acc[4] += e * b.x; acc[5] += e * b.y; acc[6] += e * b.z; acc[7] += e * b.w;

            a = an; b = bn; wv = wn;
        }
    }

    // flash-combine the 4 groups (xor 16, then 32)
    #pragma unroll
    for (int off = 16; off <= 32; off <<= 1) {
        float mo = __shfl_xor(mg, off);
        float so = __shfl_xor(ssum, off);
        float ao[8];
        #pragma unroll
        for (int j = 0; j < 8; ++j) ao[j] = __shfl_xor(acc[j], off);
        float mc = fmaxf(mg, mo);
        float s1 = (mg > -1e37f) ? __expf(mg - mc) : 0.f;   // -inf guard: empty
        float s2 = (mo > -1e37f) ? __expf(mo - mc) : 0.f;
        ssum = ssum * s1 + so * s2;
        #pragma unroll
        for (int j = 0; j < 8; ++j) acc[j] = acc[j] * s1 + ao[j] * s2;
        mg = mc;
    }

    float inv = 1.f / (ssum + 1e-10f);
    if (lane < 16) {
        float* tp = t + (size_t)gwid * 128 + pos * 8;
        *reinterpret_cast<float4*>(tp) =
            make_float4(acc[0]*inv, acc[1]*inv, acc[2]*inv, acc[3]*inv);
        *reinterpret_cast<float4*>(tp + 4) =
            make_float4(acc[4]*inv, acc[5]*inv, acc[6]*inv, acc[7]*inv);
    }
    if (lane == 0) sgate[gwid] = ssum * inv;   // sum of normalized gates
}

// K3: out[row][:] = t[row][:] @ Wm + sgate[row] * bm
// 512 threads: 8 waves x 8 rows = 64 rows/block; Wm staged once in 64 KiB LDS.
__global__ __launch_bounds__(512) void k3_out_gemm(
    const float* __restrict__ t, const float* __restrict__ Wm,
    const float* __restrict__ bm, const float* __restrict__ sgate,
    float* __restrict__ out, int S) {
    __shared__ float2 lwm[128][64];   // lwm[k][l] = (Wm[k][l], Wm[k][l+64])
    int tid = threadIdx.x;
    for (int idx = tid; idx < 128 * 64; idx += 512) {
        int k = idx >> 6, l = idx & 63;
        lwm[k][l] = make_float2(Wm[k * 128 + l], Wm[k * 128 + 64 + l]);
    }
    __syncthreads();

    int wave = tid >> 6, lane = tid & 63;
    int row0 = (blockIdx.x * 8 + wave) * 8;       // 8 rows per wave
    if (row0 >= S) return;

    const float* tb = t + (size_t)__builtin_amdgcn_readfirstlane(row0) * 128;

    float accx[8], accy[8];
    #pragma unroll
    for (int r = 0; r < 8; ++r) { accx[r] = 0.f; accy[r] = 0.f; }

    for (int k = 0; k < 128; k += 4) {
        float2 w0 = lwm[k][lane],     w1 = lwm[k + 1][lane];
        float2 w2 = lwm[k + 2][lane], w3 = lwm[k + 3][lane];
        #pragma unroll
        for (int r = 0; r < 8; ++r) {
            const float* tr = tb + r * 128 + k;   // uniform -> s_load
            float t0 = tr[0], t1 = tr[1], t2 = tr[2], t3 = tr[3];
            accx[r] += t0 * w0.x; accy[r] += t0 * w0.y;
            accx[r] += t1 * w1.x; accy[r] += t1 * w1.y;
            accx[r] += t2 * w2.x; accy[r] += t2 * w2.y;
            accx[r] += t3 * w3.x; accy[r] += t3 * w3.y;
        }
    }

    float bmx = bm[lane], bmy = bm[lane + 64];
    #pragma unroll
    for (int r = 0; r < 8; ++r) {
        int row = row0 + r;
        if (row < S) {
            float sg = sgate[row];
            out[(size_t)row * 128 + lane]      = accx[r] + sg * bmx;
            out[(size_t)row * 128 + lane + 64] = accy[r] + sg * bmy;
        }
    }
}

extern "C" void kernel_launch(void* const* d_in, const int* in_sizes, int n_in,
                              void* d_out, int out_size, void* d_ws, size_t ws_size,
                              hipStream_t stream) {
    const float* x       = (const float*)d_in[0];
    const float* weights = (const float*)d_in[1];
    const float* Wg      = (const float*)d_in[2];
    const float* bg      = (const float*)d_in[3];
    const float* Wm      = (const float*)d_in[4];
    const float* bm      = (const float*)d_in[5];
    const float* pow_    = (const float*)d_in[6];
    const int*   index   = (const int*)d_in[7];
    float* out = (float*)d_out;

    int N = in_sizes[1];          // weights is [N,1]
    int S = out_size / 128;       // out is [S,128]

    // workspace layout
    char* ws = (char*)d_ws;
    int* seg_start = (int*)ws;                                  // (S+1) ints
    size_t off = (((size_t)(S + 1) * 4) + 255) & ~(size_t)255;
    float* sgate = (float*)(ws + off);                          // S floats
    off += (((size_t)S * 4) + 255) & ~(size_t)255;
    float* t = (float*)(ws + off);                              // (S+64)*128 floats (pad for K3 over-read)

    k1_seg_offsets<<<(N + 255) / 256, 256, 0, stream>>>(index, seg_start, N, S);
    k2_seg_softmax_pool<<<(S + 3) / 4, 256, 0, stream>>>(x, weights, Wg, bg, pow_,
                                                         seg_start, t, sgate, S);
    k3_out_gemm<<<(S + 63) / 64, 512, 0, stream>>>(t, Wm, bm, sgate, out, S);
}